// Round 1
// baseline (274.053 us; speedup 1.0000x reference)
//
#include <hip/hip_runtime.h>
#include <hip/hip_bf16.h>

#define N_NODES 100000
#define N_EDGES 800000
#define HIDDEN 128

// ---------------------------------------------------------------------------
// Stage 1: per-node precompute (the key algebraic restructuring):
//   U[n] = z[n] @ W1[:128]  + b1   (stored bf16)
//   V[n] = z[n] @ W1[128:]         (stored bf16)
// Then per edge: score = relu(U[src] + V[dst]) . W2 + b2
// This replaces a 2*128*128 matvec per EDGE (52 GFLOP) with one per NODE
// (6.5 GFLOP) + a cheap per-edge gather/dot.
//
// Tiling: block = 256 threads, tile = 64 rows x 256 cols.
// Thread t: rows r0..r0+31 (r0 = (t>>7)*32), column c = t&127 for BOTH U and
// V halves -> each LDS float4 broadcast read feeds 8 FMAs (VALU-bound).
// ---------------------------------------------------------------------------
__global__ __launch_bounds__(256) void precompute_uv(
    const float* __restrict__ z, const float* __restrict__ W1,
    const float* __restrict__ b1,
    __hip_bfloat16* __restrict__ U, __hip_bfloat16* __restrict__ V)
{
    __shared__ float zs[64 * HIDDEN];   // 32 KB z tile
    const int t = threadIdx.x;
    const int n0 = blockIdx.x * 64;

    // Cooperative coalesced load of the 64x128 z tile (float4 per thread x8).
    {
        const float4* zsrc = (const float4*)z;
        float4* zdst = (float4*)zs;
        #pragma unroll
        for (int i = 0; i < 8; ++i) {
            int flat4 = i * 256 + t;           // 0..2047
            int r = flat4 >> 5;                // row in tile
            int n = n0 + r;
            float4 v = make_float4(0.f, 0.f, 0.f, 0.f);
            if (n < N_NODES) v = zsrc[(size_t)n * 32 + (flat4 & 31)];
            zdst[flat4] = v;
        }
    }
    __syncthreads();

    const int c  = t & 127;
    const int r0 = (t >> 7) * 32;
    const float* Wu = W1 + c;                    // W1 rows 0..127  (src half)
    const float* Wv = W1 + HIDDEN * HIDDEN + c;  // W1 rows 128..255 (dst half)

    float accU[32], accV[32];
    #pragma unroll
    for (int r = 0; r < 32; ++r) { accU[r] = 0.f; accV[r] = 0.f; }

    const float4* zs4 = (const float4*)zs;
    for (int k4 = 0; k4 < 32; ++k4) {
        // 8 weight scalars (coalesced across lanes, L2-hot: W1 is 128 KB)
        float wu0 = Wu[(k4 * 4 + 0) * HIDDEN];
        float wu1 = Wu[(k4 * 4 + 1) * HIDDEN];
        float wu2 = Wu[(k4 * 4 + 2) * HIDDEN];
        float wu3 = Wu[(k4 * 4 + 3) * HIDDEN];
        float wv0 = Wv[(k4 * 4 + 0) * HIDDEN];
        float wv1 = Wv[(k4 * 4 + 1) * HIDDEN];
        float wv2 = Wv[(k4 * 4 + 2) * HIDDEN];
        float wv3 = Wv[(k4 * 4 + 3) * HIDDEN];
        #pragma unroll
        for (int r = 0; r < 32; ++r) {
            float4 zv = zs4[(r0 + r) * 32 + k4];   // broadcast LDS read
            accU[r] += zv.x * wu0 + zv.y * wu1 + zv.z * wu2 + zv.w * wu3;
            accV[r] += zv.x * wv0 + zv.y * wv1 + zv.z * wv2 + zv.w * wv3;
        }
    }

    const float bias = b1[c];
    #pragma unroll
    for (int r = 0; r < 32; ++r) {
        int n = n0 + r0 + r;
        if (n < N_NODES) {
            U[(size_t)n * HIDDEN + c] = __float2bfloat16(accU[r] + bias);
            V[(size_t)n * HIDDEN + c] = __float2bfloat16(accV[r]);
        }
    }
}

// ---------------------------------------------------------------------------
// Stage 2: per-edge score = relu(U[src] + V[dst]) . W2 + b2
// 16 lanes per edge, 8 bf16 elements per lane (one uint4 = 16 B load per
// table). Each edge row is 256 B contiguous. shfl_xor width-16 reduction.
// ---------------------------------------------------------------------------
__device__ inline float2 bf2(unsigned u) {
    union { unsigned i; float f; } lo, hi;
    lo.i = u << 16;
    hi.i = u & 0xffff0000u;
    return make_float2(lo.f, hi.f);
}

__global__ __launch_bounds__(256) void edge_score(
    const int* __restrict__ ei,
    const unsigned short* __restrict__ U, const unsigned short* __restrict__ V,
    const float* __restrict__ W2, const float* __restrict__ B2,
    float* __restrict__ out)
{
    const int t = threadIdx.x;
    const int g = t & 15;                       // element group within edge
    const int e = blockIdx.x * 16 + (t >> 4);   // 16 edges per block

    // Per-lane W2 fragment: elements g*8 .. g*8+7
    const float4* W24 = (const float4*)W2;
    const float4 wa = W24[g * 2 + 0];
    const float4 wb = W24[g * 2 + 1];

    float sum = 0.f;
    if (e < N_EDGES) {
        const int src = ei[e];
        const int dst = ei[N_EDGES + e];
        const uint4* up = (const uint4*)(U + (size_t)src * HIDDEN);
        const uint4* vp = (const uint4*)(V + (size_t)dst * HIDDEN);
        const uint4 uu = up[g];
        const uint4 vv = vp[g];

        const float2 u0 = bf2(uu.x), u1 = bf2(uu.y), u2 = bf2(uu.z), u3 = bf2(uu.w);
        const float2 v0 = bf2(vv.x), v1 = bf2(vv.y), v2 = bf2(vv.z), v3 = bf2(vv.w);

        sum  = fmaxf(u0.x + v0.x, 0.f) * wa.x;
        sum += fmaxf(u0.y + v0.y, 0.f) * wa.y;
        sum += fmaxf(u1.x + v1.x, 0.f) * wa.z;
        sum += fmaxf(u1.y + v1.y, 0.f) * wa.w;
        sum += fmaxf(u2.x + v2.x, 0.f) * wb.x;
        sum += fmaxf(u2.y + v2.y, 0.f) * wb.y;
        sum += fmaxf(u3.x + v3.x, 0.f) * wb.z;
        sum += fmaxf(u3.y + v3.y, 0.f) * wb.w;
    }

    // Butterfly reduce across the 16 lanes of this edge.
    sum += __shfl_xor(sum, 1, 16);
    sum += __shfl_xor(sum, 2, 16);
    sum += __shfl_xor(sum, 4, 16);
    sum += __shfl_xor(sum, 8, 16);

    if (g == 0 && e < N_EDGES) out[e] = sum + B2[0];
}

extern "C" void kernel_launch(void* const* d_in, const int* in_sizes, int n_in,
                              void* d_out, int out_size, void* d_ws, size_t ws_size,
                              hipStream_t stream) {
    const float* z  = (const float*)d_in[0];
    const int*   ei = (const int*)d_in[1];   // JAX without x64 -> int32
    const float* W1 = (const float*)d_in[2];
    const float* b1 = (const float*)d_in[3];
    const float* W2 = (const float*)d_in[4];
    const float* b2 = (const float*)d_in[5];
    float* out = (float*)d_out;

    __hip_bfloat16* U = (__hip_bfloat16*)d_ws;                    // 25.6 MB
    __hip_bfloat16* V = U + (size_t)N_NODES * HIDDEN;             // 25.6 MB
    // total ws use: 51.2 MB

    precompute_uv<<<(N_NODES + 63) / 64, 256, 0, stream>>>(z, W1, b1, U, V);
    edge_score<<<(N_EDGES + 15) / 16, 256, 0, stream>>>(
        ei, (const unsigned short*)U, (const unsigned short*)V, W2, b2, out);
}

// Round 2
// 233.064 us; speedup vs baseline: 1.1759x; 1.1759x over previous
//
#include <hip/hip_runtime.h>
#include <hip/hip_bf16.h>

#define N_NODES 100000
#define N_EDGES 800000
#define HIDDEN 128

typedef short frag_ab __attribute__((ext_vector_type(8)));   // 8 x bf16 (4 VGPRs)
typedef float frag_cd __attribute__((ext_vector_type(4)));   // 4 x f32

// round-to-nearest-even fp32 -> bf16
__device__ inline unsigned short f2b(float f) {
    union { float f; unsigned u; } x; x.f = f;
    unsigned r = (x.u + 0x7fffu + ((x.u >> 16) & 1u)) >> 16;
    return (unsigned short)r;
}

// ---------------------------------------------------------------------------
// Stage 1 (MFMA): C[100000 x 256] = z[100000 x 128] @ [W1_src | W1_dst]
//   cols 0..127  -> U (bias b1 added), cols 128..255 -> V. Stored bf16.
// Block = 256 thr = 4 waves. M-tile 64 (staged in LDS as bf16), each wave
// owns a 64-col stripe. B fragments register-resident (W1 is 128 KB,
// L2-hot across all 1563 blocks; direct scattered loads avoid the LDS
// transpose which would bank-conflict).
// A LDS row stride 136 shorts: keeps 16B alignment for ds_read_b128 and
// turns the 16-way bank conflict of stride-128 into a free 2-way.
// ---------------------------------------------------------------------------
#define AS_STRIDE 136

__global__ __launch_bounds__(256) void precompute_uv_mfma(
    const float* __restrict__ z, const float* __restrict__ W1,
    const float* __restrict__ b1,
    unsigned short* __restrict__ U, unsigned short* __restrict__ V)
{
    __shared__ unsigned short As[64 * AS_STRIDE];   // 17 KB
    const int t = threadIdx.x;
    const int m0 = blockIdx.x * 64;
    const int lane = t & 63;
    const int w = t >> 6;

    // --- stage A tile: 64 rows x 128 cols, fp32 -> bf16, coalesced ---
    #pragma unroll
    for (int i = 0; i < 8; ++i) {
        int f4 = i * 256 + t;            // float4 index 0..2047
        int m = f4 >> 5;
        int c4 = f4 & 31;
        float4 v = make_float4(0.f, 0.f, 0.f, 0.f);
        if (m0 + m < N_NODES)
            v = ((const float4*)z)[(size_t)(m0 + m) * 32 + c4];
        unsigned short* dst = &As[m * AS_STRIDE + c4 * 4];
        dst[0] = f2b(v.x); dst[1] = f2b(v.y); dst[2] = f2b(v.z); dst[3] = f2b(v.w);
    }

    // --- preload B fragments: wave w covers combined cols wn..wn+63 ---
    const int wn = w * 64;
    const int g  = lane >> 4;            // k-group 0..3
    const int lc = lane & 15;            // col within 16-tile
    frag_ab b[4][4];                     // [nt][q]
    #pragma unroll
    for (int nt = 0; nt < 4; ++nt) {
        int nc = wn + nt * 16 + lc;      // combined col 0..255
        const float* bsrc = (nc < HIDDEN) ? (W1 + nc)
                                          : (W1 + HIDDEN * HIDDEN + (nc - HIDDEN));
        #pragma unroll
        for (int q = 0; q < 4; ++q) {
            int kb = q * 32 + g * 8;
            frag_ab f;
            #pragma unroll
            for (int j = 0; j < 8; ++j)
                f[j] = (short)f2b(bsrc[(size_t)(kb + j) * HIDDEN]);
            b[nt][q] = f;
        }
    }

    frag_cd acc[4][4];
    #pragma unroll
    for (int mt = 0; mt < 4; ++mt)
        #pragma unroll
        for (int nt = 0; nt < 4; ++nt)
            acc[mt][nt] = (frag_cd){0.f, 0.f, 0.f, 0.f};

    __syncthreads();

    // --- K loop: 16 ds_read_b128 + 64 MFMA per wave total ---
    #pragma unroll
    for (int q = 0; q < 4; ++q) {
        frag_ab a[4];
        #pragma unroll
        for (int mt = 0; mt < 4; ++mt)
            a[mt] = *(const frag_ab*)&As[(mt * 16 + lc) * AS_STRIDE + q * 32 + g * 8];
        #pragma unroll
        for (int mt = 0; mt < 4; ++mt)
            #pragma unroll
            for (int nt = 0; nt < 4; ++nt)
                acc[mt][nt] = __builtin_amdgcn_mfma_f32_16x16x32_bf16(
                    a[mt], b[nt][q], acc[mt][nt], 0, 0, 0);
    }

    // --- epilogue: C layout col=lane&15, row=(lane>>4)*4+reg (verified) ---
    #pragma unroll
    for (int nt = 0; nt < 4; ++nt) {
        int nc = wn + nt * 16 + lc;
        float bias = (nc < HIDDEN) ? b1[nc] : 0.f;
        unsigned short* outp = (nc < HIDDEN) ? (U + nc) : (V + (nc - HIDDEN));
        #pragma unroll
        for (int mt = 0; mt < 4; ++mt) {
            #pragma unroll
            for (int r = 0; r < 4; ++r) {
                int m = m0 + mt * 16 + g * 4 + r;
                if (m < N_NODES)
                    outp[(size_t)m * HIDDEN] = f2b(acc[mt][nt][r] + bias);
            }
        }
    }
}

// ---------------------------------------------------------------------------
// Stage 2: per-edge score = relu(U[src] + V[dst]) . W2 + b2  (unchanged)
// ---------------------------------------------------------------------------
__device__ inline float2 bf2(unsigned u) {
    union { unsigned i; float f; } lo, hi;
    lo.i = u << 16;
    hi.i = u & 0xffff0000u;
    return make_float2(lo.f, hi.f);
}

__global__ __launch_bounds__(256) void edge_score(
    const int* __restrict__ ei,
    const unsigned short* __restrict__ U, const unsigned short* __restrict__ V,
    const float* __restrict__ W2, const float* __restrict__ B2,
    float* __restrict__ out)
{
    const int t = threadIdx.x;
    const int g = t & 15;
    const int e = blockIdx.x * 16 + (t >> 4);

    const float4* W24 = (const float4*)W2;
    const float4 wa = W24[g * 2 + 0];
    const float4 wb = W24[g * 2 + 1];

    float sum = 0.f;
    if (e < N_EDGES) {
        const int src = ei[e];
        const int dst = ei[N_EDGES + e];
        const uint4 uu = ((const uint4*)(U + (size_t)src * HIDDEN))[g];
        const uint4 vv = ((const uint4*)(V + (size_t)dst * HIDDEN))[g];

        const float2 u0 = bf2(uu.x), u1 = bf2(uu.y), u2 = bf2(uu.z), u3 = bf2(uu.w);
        const float2 v0 = bf2(vv.x), v1 = bf2(vv.y), v2 = bf2(vv.z), v3 = bf2(vv.w);

        sum  = fmaxf(u0.x + v0.x, 0.f) * wa.x;
        sum += fmaxf(u0.y + v0.y, 0.f) * wa.y;
        sum += fmaxf(u1.x + v1.x, 0.f) * wa.z;
        sum += fmaxf(u1.y + v1.y, 0.f) * wa.w;
        sum += fmaxf(u2.x + v2.x, 0.f) * wb.x;
        sum += fmaxf(u2.y + v2.y, 0.f) * wb.y;
        sum += fmaxf(u3.x + v3.x, 0.f) * wb.z;
        sum += fmaxf(u3.y + v3.y, 0.f) * wb.w;
    }

    sum += __shfl_xor(sum, 1, 16);
    sum += __shfl_xor(sum, 2, 16);
    sum += __shfl_xor(sum, 4, 16);
    sum += __shfl_xor(sum, 8, 16);

    if (g == 0 && e < N_EDGES) out[e] = sum + B2[0];
}

extern "C" void kernel_launch(void* const* d_in, const int* in_sizes, int n_in,
                              void* d_out, int out_size, void* d_ws, size_t ws_size,
                              hipStream_t stream) {
    const float* z  = (const float*)d_in[0];
    const int*   ei = (const int*)d_in[1];
    const float* W1 = (const float*)d_in[2];
    const float* b1 = (const float*)d_in[3];
    const float* W2 = (const float*)d_in[4];
    const float* b2 = (const float*)d_in[5];
    float* out = (float*)d_out;

    unsigned short* U = (unsigned short*)d_ws;               // 25.6 MB
    unsigned short* V = U + (size_t)N_NODES * HIDDEN;        // 25.6 MB

    precompute_uv_mfma<<<(N_NODES + 63) / 64, 256, 0, stream>>>(z, W1, b1, U, V);
    edge_score<<<(N_EDGES + 15) / 16, 256, 0, stream>>>(
        ei, U, V, W2, b2, out);
}

// Round 3
// 180.466 us; speedup vs baseline: 1.5186x; 1.2915x over previous
//
#include <hip/hip_runtime.h>
#include <hip/hip_bf16.h>

#define N_NODES 100000
#define N_EDGES 800000
#define HIDDEN 128

typedef short frag_ab __attribute__((ext_vector_type(8)));   // 8 x bf16 (4 VGPRs)
typedef float frag_cd __attribute__((ext_vector_type(4)));   // 4 x f32

// round-to-nearest-even fp32 -> bf16
__device__ inline unsigned short f2b(float f) {
    union { float f; unsigned u; } x; x.f = f;
    return (unsigned short)((x.u + 0x7fffu + ((x.u >> 16) & 1u)) >> 16);
}

// ---------------------------------------------------------------------------
// Kernel 0: transpose+convert W1 (256x128 fp32, row=k) into Bt[256][128] bf16
// where Bt[nc][k] = combined-B column nc, k-contiguous. 64 KB, stays L2-hot.
// nc < 128 -> W1 rows 0..127 (src half); nc >= 128 -> rows 128..255 (dst).
// grid 64 x 256 thr: block b covers nc = 4b..4b+3; lane pair-packs 2 k's.
// ---------------------------------------------------------------------------
__global__ __launch_bounds__(256) void transpose_w1(
    const float* __restrict__ W1, unsigned short* __restrict__ Bt)
{
    const int t  = threadIdx.x;
    const int nc = blockIdx.x * 4 + (t >> 6);
    const int k2 = (t & 63) * 2;
    const int col  = nc & 127;
    const int roff = (nc >= 128) ? 128 : 0;
    float f0 = W1[(size_t)(roff + k2)     * HIDDEN + col];
    float f1 = W1[(size_t)(roff + k2 + 1) * HIDDEN + col];
    unsigned pack = (unsigned)f2b(f0) | ((unsigned)f2b(f1) << 16);
    *(unsigned*)(Bt + (size_t)nc * HIDDEN + k2) = pack;
}

// ---------------------------------------------------------------------------
// Kernel 1 (MFMA GEMM): UV[100000 x 256] = z[100000 x 128] @ Bt^T, bf16 out.
//   cols 0..127 get +b1 (U half), cols 128..255 are V half.
// Block = 4 waves, tile 64 rows x 256 cols (64-col stripe per wave).
// A staged in LDS (stride 136 shorts: 16B-aligned, 2-way bank alias = free).
// B fragments: 16 contiguous dwordx4 loads from Bt per thread (L2-hot).
// Epilogue: acc -> LDS (stride 264) -> coalesced uint4 stores of UV rows.
// ---------------------------------------------------------------------------
#define AS_STRIDE 136
#define CS_STRIDE 264

__global__ __launch_bounds__(256) void precompute_uv_mfma(
    const float* __restrict__ z, const unsigned short* __restrict__ Bt,
    const float* __restrict__ b1, unsigned short* __restrict__ UV)
{
    __shared__ unsigned short smem[64 * CS_STRIDE];   // 33 KB, A then C
    const int t = threadIdx.x;
    const int m0 = blockIdx.x * 64;
    const int lane = t & 63;
    const int w = t >> 6;

    // --- stage A tile: 64 x 128 fp32 -> bf16, one ds_write_b64 per float4 ---
    #pragma unroll
    for (int i = 0; i < 8; ++i) {
        int f4 = i * 256 + t;            // float4 index 0..2047
        int m = f4 >> 5;
        int c4 = f4 & 31;
        float4 v = make_float4(0.f, 0.f, 0.f, 0.f);
        if (m0 + m < N_NODES)
            v = ((const float4*)z)[(size_t)(m0 + m) * 32 + c4];
        uint2 p;
        p.x = (unsigned)f2b(v.x) | ((unsigned)f2b(v.y) << 16);
        p.y = (unsigned)f2b(v.z) | ((unsigned)f2b(v.w) << 16);
        *(uint2*)&smem[m * AS_STRIDE + c4 * 4] = p;
    }

    // --- B fragments: wave w covers combined cols wn..wn+63 ---
    const int wn = w * 64;
    const int g  = lane >> 4;            // k-group 0..3
    const int lc = lane & 15;            // col within 16-tile
    frag_ab b[4][4];                     // [nt][q]
    #pragma unroll
    for (int nt = 0; nt < 4; ++nt) {
        const unsigned short* brow = Bt + (size_t)(wn + nt * 16 + lc) * HIDDEN;
        #pragma unroll
        for (int q = 0; q < 4; ++q)
            b[nt][q] = *(const frag_ab*)(brow + q * 32 + g * 8);  // 16 B contiguous
    }

    frag_cd acc[4][4];
    #pragma unroll
    for (int mt = 0; mt < 4; ++mt)
        #pragma unroll
        for (int nt = 0; nt < 4; ++nt)
            acc[mt][nt] = (frag_cd){0.f, 0.f, 0.f, 0.f};

    __syncthreads();

    // --- K loop: 16 ds_read_b128 + 64 MFMA per wave ---
    #pragma unroll
    for (int q = 0; q < 4; ++q) {
        frag_ab a[4];
        #pragma unroll
        for (int mt = 0; mt < 4; ++mt)
            a[mt] = *(const frag_ab*)&smem[(mt * 16 + lc) * AS_STRIDE + q * 32 + g * 8];
        #pragma unroll
        for (int mt = 0; mt < 4; ++mt)
            #pragma unroll
            for (int nt = 0; nt < 4; ++nt)
                acc[mt][nt] = __builtin_amdgcn_mfma_f32_16x16x32_bf16(
                    a[mt], b[nt][q], acc[mt][nt], 0, 0, 0);
    }

    __syncthreads();   // all A reads done before smem is reused for C

    // --- C -> LDS (bf16), C layout col=lane&15, row=(lane>>4)*4+reg ---
    #pragma unroll
    for (int nt = 0; nt < 4; ++nt) {
        int nc = wn + nt * 16 + lc;
        float bias = (nc < HIDDEN) ? b1[nc] : 0.f;
        #pragma unroll
        for (int mt = 0; mt < 4; ++mt)
            #pragma unroll
            for (int r = 0; r < 4; ++r)
                smem[(mt * 16 + g * 4 + r) * CS_STRIDE + nc] =
                    f2b(acc[mt][nt][r] + bias);
    }

    __syncthreads();

    // --- coalesced store: UV row = 256 shorts = 512 B contiguous per node ---
    #pragma unroll
    for (int i = 0; i < 8; ++i) {
        int f = i * 256 + t;             // uint4 index 0..2047
        int m = f >> 5;
        int c16 = f & 31;
        if (m0 + m < N_NODES) {
            uint4 val = *(const uint4*)&smem[m * CS_STRIDE + c16 * 8];
            *(uint4*)&UV[(size_t)(m0 + m) * 256 + c16 * 8] = val;
        }
    }
}

// ---------------------------------------------------------------------------
// Kernel 2: per-edge score = relu(U[src] + V[dst]) . W2 + b2
// UV layout: node row = [U(128) | V(128)] bf16, 512 B contiguous.
// 16 lanes/edge, one uint4 (8 bf16) per lane per table, shfl_xor reduce.
// ---------------------------------------------------------------------------
__device__ inline float2 bf2(unsigned u) {
    union { unsigned i; float f; } lo, hi;
    lo.i = u << 16;
    hi.i = u & 0xffff0000u;
    return make_float2(lo.f, hi.f);
}

__global__ __launch_bounds__(256) void edge_score(
    const int* __restrict__ ei, const unsigned short* __restrict__ UV,
    const float* __restrict__ W2, const float* __restrict__ B2,
    float* __restrict__ out)
{
    const int t = threadIdx.x;
    const int g = t & 15;
    const int e = blockIdx.x * 16 + (t >> 4);

    const float4* W24 = (const float4*)W2;
    const float4 wa = W24[g * 2 + 0];
    const float4 wb = W24[g * 2 + 1];

    float sum = 0.f;
    if (e < N_EDGES) {
        const int src = ei[e];
        const int dst = ei[N_EDGES + e];
        const uint4 uu = ((const uint4*)(UV + (size_t)src * 256))[g];
        const uint4 vv = ((const uint4*)(UV + (size_t)dst * 256 + 128))[g];

        const float2 u0 = bf2(uu.x), u1 = bf2(uu.y), u2 = bf2(uu.z), u3 = bf2(uu.w);
        const float2 v0 = bf2(vv.x), v1 = bf2(vv.y), v2 = bf2(vv.z), v3 = bf2(vv.w);

        sum  = fmaxf(u0.x + v0.x, 0.f) * wa.x;
        sum += fmaxf(u0.y + v0.y, 0.f) * wa.y;
        sum += fmaxf(u1.x + v1.x, 0.f) * wa.z;
        sum += fmaxf(u1.y + v1.y, 0.f) * wa.w;
        sum += fmaxf(u2.x + v2.x, 0.f) * wb.x;
        sum += fmaxf(u2.y + v2.y, 0.f) * wb.y;
        sum += fmaxf(u3.x + v3.x, 0.f) * wb.z;
        sum += fmaxf(u3.y + v3.y, 0.f) * wb.w;
    }

    sum += __shfl_xor(sum, 1, 16);
    sum += __shfl_xor(sum, 2, 16);
    sum += __shfl_xor(sum, 4, 16);
    sum += __shfl_xor(sum, 8, 16);

    if (g == 0 && e < N_EDGES) out[e] = sum + B2[0];
}

extern "C" void kernel_launch(void* const* d_in, const int* in_sizes, int n_in,
                              void* d_out, int out_size, void* d_ws, size_t ws_size,
                              hipStream_t stream) {
    const float* z  = (const float*)d_in[0];
    const int*   ei = (const int*)d_in[1];
    const float* W1 = (const float*)d_in[2];
    const float* b1 = (const float*)d_in[3];
    const float* W2 = (const float*)d_in[4];
    const float* b2 = (const float*)d_in[5];
    float* out = (float*)d_out;

    unsigned short* UV = (unsigned short*)d_ws;                 // 51.2 MB
    unsigned short* Bt = UV + (size_t)N_NODES * 256;            // 64 KB

    transpose_w1<<<64, 256, 0, stream>>>(W1, Bt);
    precompute_uv_mfma<<<(N_NODES + 63) / 64, 256, 0, stream>>>(z, Bt, b1, UV);
    edge_score<<<(N_EDGES + 15) / 16, 256, 0, stream>>>(ei, UV, W2, b2, out);
}

// Round 4
// 174.829 us; speedup vs baseline: 1.5676x; 1.0322x over previous
//
#include <hip/hip_runtime.h>
#include <hip/hip_bf16.h>

#define N_NODES 100000
#define N_EDGES 800000
#define HIDDEN 128

typedef short frag_ab __attribute__((ext_vector_type(8)));   // 8 x bf16 (4 VGPRs)
typedef float frag_cd __attribute__((ext_vector_type(4)));   // 4 x f32

// round-to-nearest-even fp32 -> bf16
__device__ inline unsigned short f2b(float f) {
    union { float f; unsigned u; } x; x.f = f;
    return (unsigned short)((x.u + 0x7fffu + ((x.u >> 16) & 1u)) >> 16);
}

// ---------------------------------------------------------------------------
// Kernel 0: transpose+convert W1 (256x128 fp32, row=k) into Bt[256][128] bf16
// ---------------------------------------------------------------------------
__global__ __launch_bounds__(256) void transpose_w1(
    const float* __restrict__ W1, unsigned short* __restrict__ Bt)
{
    const int t  = threadIdx.x;
    const int nc = blockIdx.x * 4 + (t >> 6);
    const int k2 = (t & 63) * 2;
    const int col  = nc & 127;
    const int roff = (nc >= 128) ? 128 : 0;
    float f0 = W1[(size_t)(roff + k2)     * HIDDEN + col];
    float f1 = W1[(size_t)(roff + k2 + 1) * HIDDEN + col];
    unsigned pack = (unsigned)f2b(f0) | ((unsigned)f2b(f1) << 16);
    *(unsigned*)(Bt + (size_t)nc * HIDDEN + k2) = pack;
}

// ---------------------------------------------------------------------------
// Kernel 1 (MFMA GEMM): UV[100000 x 256] = z[100000 x 128] @ Bt^T, bf16 out.
// (unchanged from R3 — single-variable discipline; edge_score is the experiment)
// ---------------------------------------------------------------------------
#define AS_STRIDE 136
#define CS_STRIDE 264

__global__ __launch_bounds__(256) void precompute_uv_mfma(
    const float* __restrict__ z, const unsigned short* __restrict__ Bt,
    const float* __restrict__ b1, unsigned short* __restrict__ UV)
{
    __shared__ unsigned short smem[64 * CS_STRIDE];   // 33 KB, A then C
    const int t = threadIdx.x;
    const int m0 = blockIdx.x * 64;
    const int lane = t & 63;
    const int w = t >> 6;

    #pragma unroll
    for (int i = 0; i < 8; ++i) {
        int f4 = i * 256 + t;
        int m = f4 >> 5;
        int c4 = f4 & 31;
        float4 v = make_float4(0.f, 0.f, 0.f, 0.f);
        if (m0 + m < N_NODES)
            v = ((const float4*)z)[(size_t)(m0 + m) * 32 + c4];
        uint2 p;
        p.x = (unsigned)f2b(v.x) | ((unsigned)f2b(v.y) << 16);
        p.y = (unsigned)f2b(v.z) | ((unsigned)f2b(v.w) << 16);
        *(uint2*)&smem[m * AS_STRIDE + c4 * 4] = p;
    }

    const int wn = w * 64;
    const int g  = lane >> 4;
    const int lc = lane & 15;
    frag_ab b[4][4];
    #pragma unroll
    for (int nt = 0; nt < 4; ++nt) {
        const unsigned short* brow = Bt + (size_t)(wn + nt * 16 + lc) * HIDDEN;
        #pragma unroll
        for (int q = 0; q < 4; ++q)
            b[nt][q] = *(const frag_ab*)(brow + q * 32 + g * 8);
    }

    frag_cd acc[4][4];
    #pragma unroll
    for (int mt = 0; mt < 4; ++mt)
        #pragma unroll
        for (int nt = 0; nt < 4; ++nt)
            acc[mt][nt] = (frag_cd){0.f, 0.f, 0.f, 0.f};

    __syncthreads();

    #pragma unroll
    for (int q = 0; q < 4; ++q) {
        frag_ab a[4];
        #pragma unroll
        for (int mt = 0; mt < 4; ++mt)
            a[mt] = *(const frag_ab*)&smem[(mt * 16 + lc) * AS_STRIDE + q * 32 + g * 8];
        #pragma unroll
        for (int mt = 0; mt < 4; ++mt)
            #pragma unroll
            for (int nt = 0; nt < 4; ++nt)
                acc[mt][nt] = __builtin_amdgcn_mfma_f32_16x16x32_bf16(
                    a[mt], b[nt][q], acc[mt][nt], 0, 0, 0);
    }

    __syncthreads();

    #pragma unroll
    for (int nt = 0; nt < 4; ++nt) {
        int nc = wn + nt * 16 + lc;
        float bias = (nc < HIDDEN) ? b1[nc] : 0.f;
        #pragma unroll
        for (int mt = 0; mt < 4; ++mt)
            #pragma unroll
            for (int r = 0; r < 4; ++r)
                smem[(mt * 16 + g * 4 + r) * CS_STRIDE + nc] =
                    f2b(acc[mt][nt][r] + bias);
    }

    __syncthreads();

    #pragma unroll
    for (int i = 0; i < 8; ++i) {
        int f = i * 256 + t;
        int m = f >> 5;
        int c16 = f & 31;
        if (m0 + m < N_NODES) {
            uint4 val = *(const uint4*)&smem[m * CS_STRIDE + c16 * 8];
            *(uint4*)&UV[(size_t)(m0 + m) * 256 + c16 * 8] = val;
        }
    }
}

// ---------------------------------------------------------------------------
// Kernel 2: per-edge score = relu(U[src] + V[dst]) . W2 + b2
// 8 lanes/edge, 16 elements/lane (2 x uint4 per table = 4 outstanding 16B
// loads per lane -> 2x MLP vs R3). Math in float2 to get packed
// v_pk_add/max/fma_f32. 3-stage shfl_xor reduce. 32 edges per 256-thr block.
// ---------------------------------------------------------------------------
__device__ inline float2 bf2(unsigned u) {
    union { unsigned i; float f; } lo, hi;
    lo.i = u << 16;
    hi.i = u & 0xffff0000u;
    return make_float2(lo.f, hi.f);
}

__device__ inline float2 rfma2(unsigned u, unsigned v, float2 w, float2 acc) {
    float2 uf = bf2(u), vf = bf2(v);
    float2 s = make_float2(uf.x + vf.x, uf.y + vf.y);        // v_pk_add_f32
    s.x = fmaxf(s.x, 0.f); s.y = fmaxf(s.y, 0.f);            // v_pk_max_f32
    acc.x = __builtin_fmaf(s.x, w.x, acc.x);                  // v_pk_fma_f32
    acc.y = __builtin_fmaf(s.y, w.y, acc.y);
    return acc;
}

__global__ __launch_bounds__(256) void edge_score(
    const int* __restrict__ ei, const unsigned short* __restrict__ UV,
    const float* __restrict__ W2, const float* __restrict__ B2,
    float* __restrict__ out)
{
    const int t = threadIdx.x;
    const int g = t & 7;                        // lane's 16-element group
    const int e = blockIdx.x * 32 + (t >> 3);   // 32 edges per block

    // W2 fragment: elements g*16 .. g*16+15
    const float4* W24 = (const float4*)W2;
    const float4 w0 = W24[g * 4 + 0];
    const float4 w1 = W24[g * 4 + 1];
    const float4 w2 = W24[g * 4 + 2];
    const float4 w3 = W24[g * 4 + 3];

    float2 s2 = make_float2(0.f, 0.f);
    if (e < N_EDGES) {
        const int src = ei[e];
        const int dst = ei[N_EDGES + e];
        const uint4* up = (const uint4*)(UV + (size_t)src * 256) + g * 2;
        const uint4* vp = (const uint4*)(UV + (size_t)dst * 256 + 128) + g * 2;
        const uint4 ua = up[0];
        const uint4 ub = up[1];
        const uint4 va = vp[0];
        const uint4 vb = vp[1];

        s2 = rfma2(ua.x, va.x, make_float2(w0.x, w0.y), s2);
        s2 = rfma2(ua.y, va.y, make_float2(w0.z, w0.w), s2);
        s2 = rfma2(ua.z, va.z, make_float2(w1.x, w1.y), s2);
        s2 = rfma2(ua.w, va.w, make_float2(w1.z, w1.w), s2);
        s2 = rfma2(ub.x, vb.x, make_float2(w2.x, w2.y), s2);
        s2 = rfma2(ub.y, vb.y, make_float2(w2.z, w2.w), s2);
        s2 = rfma2(ub.z, vb.z, make_float2(w3.x, w3.y), s2);
        s2 = rfma2(ub.w, vb.w, make_float2(w3.z, w3.w), s2);
    }

    float sum = s2.x + s2.y;
    sum += __shfl_xor(sum, 1, 8);
    sum += __shfl_xor(sum, 2, 8);
    sum += __shfl_xor(sum, 4, 8);

    if (g == 0 && e < N_EDGES) out[e] = sum + B2[0];
}

extern "C" void kernel_launch(void* const* d_in, const int* in_sizes, int n_in,
                              void* d_out, int out_size, void* d_ws, size_t ws_size,
                              hipStream_t stream) {
    const float* z  = (const float*)d_in[0];
    const int*   ei = (const int*)d_in[1];
    const float* W1 = (const float*)d_in[2];
    const float* b1 = (const float*)d_in[3];
    const float* W2 = (const float*)d_in[4];
    const float* b2 = (const float*)d_in[5];
    float* out = (float*)d_out;

    unsigned short* UV = (unsigned short*)d_ws;                 // 51.2 MB
    unsigned short* Bt = UV + (size_t)N_NODES * 256;            // 64 KB

    transpose_w1<<<64, 256, 0, stream>>>(W1, Bt);
    precompute_uv_mfma<<<(N_NODES + 63) / 64, 256, 0, stream>>>(z, Bt, b1, UV);
    edge_score<<<(N_EDGES + 31) / 32, 256, 0, stream>>>(ei, UV, W2, b2, out);
}

// Round 5
// 165.973 us; speedup vs baseline: 1.6512x; 1.0534x over previous
//
#include <hip/hip_runtime.h>
#include <hip/hip_bf16.h>

#define N_NODES 100000
#define N_EDGES 800000
#define HIDDEN 128
#define N_TILES 1563            // ceil(100000 / 64)
#define PC_GRID 768             // 3 blocks/CU capacity; grid-stride over tiles

typedef short frag_ab __attribute__((ext_vector_type(8)));   // 8 x bf16
typedef float frag_cd __attribute__((ext_vector_type(4)));   // 4 x f32

// round-to-nearest-even fp32 -> bf16
__device__ inline unsigned short f2b(float f) {
    union { float f; unsigned u; } x; x.f = f;
    return (unsigned short)((x.u + 0x7fffu + ((x.u >> 16) & 1u)) >> 16);
}

// ---------------------------------------------------------------------------
// Kernel 0: transpose+convert W1 (256x128 fp32) -> Bt[256][128] bf16, k-contig.
// ---------------------------------------------------------------------------
__global__ __launch_bounds__(256) void transpose_w1(
    const float* __restrict__ W1, unsigned short* __restrict__ Bt)
{
    const int t  = threadIdx.x;
    const int nc = blockIdx.x * 4 + (t >> 6);
    const int k2 = (t & 63) * 2;
    const int col  = nc & 127;
    const int roff = (nc >= 128) ? 128 : 0;
    float f0 = W1[(size_t)(roff + k2)     * HIDDEN + col];
    float f1 = W1[(size_t)(roff + k2 + 1) * HIDDEN + col];
    unsigned pack = (unsigned)f2b(f0) | ((unsigned)f2b(f1) << 16);
    *(unsigned*)(Bt + (size_t)nc * HIDDEN + k2) = pack;
}

// ---------------------------------------------------------------------------
// Kernel 1 (MFMA GEMM, persistent grid-stride): UV = z @ [W1src|W1dst] + [b1|0]
// Each block loops over tiles (stride PC_GRID) with cross-tile REGISTER
// PREFETCH of the next A tile: the 8 float4 z-loads for tile t+1 issue right
// after tile t's LDS staging, hiding ~900-cyc HBM latency behind MFMA+epilogue.
// B fragments + bias loaded ONCE per block. Clamped loads, guarded stores.
// LDS: A (64x136 bf16, 17.4 KB) + C (64x264 bf16, 33.8 KB) = 51.2 KB.
// ---------------------------------------------------------------------------
#define AS_STRIDE 136
#define CS_STRIDE 264

__global__ __launch_bounds__(256) void precompute_uv_mfma(
    const float* __restrict__ z, const unsigned short* __restrict__ Bt,
    const float* __restrict__ b1, unsigned short* __restrict__ UV)
{
    __shared__ unsigned short As[64 * AS_STRIDE];
    __shared__ unsigned short Cs[64 * CS_STRIDE];
    const int t = threadIdx.x;
    const int lane = t & 63;
    const int w = t >> 6;
    const int wn = w * 64;
    const int g  = lane >> 4;
    const int lc = lane & 15;

    // --- B fragments + bias: once per block (amortized over ~2-3 tiles) ---
    frag_ab b[4][4];
    float bias[4];
    #pragma unroll
    for (int nt = 0; nt < 4; ++nt) {
        int nc = wn + nt * 16 + lc;
        bias[nt] = (nc < HIDDEN) ? b1[nc] : 0.f;
        const unsigned short* brow = Bt + (size_t)nc * HIDDEN;
        #pragma unroll
        for (int q = 0; q < 4; ++q)
            b[nt][q] = *(const frag_ab*)(brow + q * 32 + g * 8);
    }

    int tile = blockIdx.x;
    float4 pf[8];
    // first tile's A prefetch (clamped rows; garbage rows never stored)
    #pragma unroll
    for (int i = 0; i < 8; ++i) {
        int f4 = i * 256 + t;
        int m = tile * 64 + (f4 >> 5);
        if (m >= N_NODES) m = N_NODES - 1;
        pf[i] = ((const float4*)z)[(size_t)m * 32 + (f4 & 31)];
    }

    while (true) {
        // --- stage A: regs -> bf16 LDS ---
        #pragma unroll
        for (int i = 0; i < 8; ++i) {
            int f4 = i * 256 + t;
            int m = f4 >> 5;
            int c4 = f4 & 31;
            uint2 p;
            p.x = (unsigned)f2b(pf[i].x) | ((unsigned)f2b(pf[i].y) << 16);
            p.y = (unsigned)f2b(pf[i].z) | ((unsigned)f2b(pf[i].w) << 16);
            *(uint2*)&As[m * AS_STRIDE + c4 * 4] = p;
        }
        __syncthreads();

        // --- prefetch NEXT tile's A while this tile computes ---
        const int next = tile + PC_GRID;
        const bool have_next = (next < N_TILES);
        if (have_next) {
            #pragma unroll
            for (int i = 0; i < 8; ++i) {
                int f4 = i * 256 + t;
                int m = next * 64 + (f4 >> 5);
                if (m >= N_NODES) m = N_NODES - 1;
                pf[i] = ((const float4*)z)[(size_t)m * 32 + (f4 & 31)];
            }
        }

        // --- K loop: 16 ds_read_b128 + 64 MFMA per wave ---
        frag_cd acc[4][4];
        #pragma unroll
        for (int mt = 0; mt < 4; ++mt)
            #pragma unroll
            for (int nt = 0; nt < 4; ++nt)
                acc[mt][nt] = (frag_cd){0.f, 0.f, 0.f, 0.f};
        #pragma unroll
        for (int q = 0; q < 4; ++q) {
            frag_ab a[4];
            #pragma unroll
            for (int mt = 0; mt < 4; ++mt)
                a[mt] = *(const frag_ab*)&As[(mt * 16 + lc) * AS_STRIDE + q * 32 + g * 8];
            #pragma unroll
            for (int mt = 0; mt < 4; ++mt)
                #pragma unroll
                for (int nt = 0; nt < 4; ++nt)
                    acc[mt][nt] = __builtin_amdgcn_mfma_f32_16x16x32_bf16(
                        a[mt], b[nt][q], acc[mt][nt], 0, 0, 0);
        }
        __syncthreads();   // A reads done (As rewritten next iter), Cs safe

        // --- epilogue: acc -> Cs (C layout col=lane&15, row=(lane>>4)*4+reg) ---
        #pragma unroll
        for (int nt = 0; nt < 4; ++nt) {
            int nc = wn + nt * 16 + lc;
            #pragma unroll
            for (int mt = 0; mt < 4; ++mt)
                #pragma unroll
                for (int r = 0; r < 4; ++r)
                    Cs[(mt * 16 + g * 4 + r) * CS_STRIDE + nc] =
                        f2b(acc[mt][nt][r] + bias[nt]);
        }
        __syncthreads();

        // --- coalesced store: 512 B contiguous per node row ---
        const int m0 = tile * 64;
        #pragma unroll
        for (int i = 0; i < 8; ++i) {
            int f = i * 256 + t;
            int m = f >> 5;
            int c16 = f & 31;
            if (m0 + m < N_NODES) {
                uint4 val = *(const uint4*)&Cs[m * CS_STRIDE + c16 * 8];
                *(uint4*)&UV[(size_t)(m0 + m) * 256 + c16 * 8] = val;
            }
        }
        if (!have_next) break;
        __syncthreads();   // Cs reads done before next epilogue overwrites
        tile = next;
    }
}

// ---------------------------------------------------------------------------
// Kernel 2: per-edge score = relu(U[src] + V[dst]) . W2 + b2
// 8 lanes/edge, TWO edges per thread (e0, e0+32): 8 outstanding 16-B gathers
// per lane (2x MLP vs R4), W2 fragment shared between both edges. Packed
// float2 math. 800000 = 12500 blocks * 64 edges exactly -> no guards.
// ---------------------------------------------------------------------------
__device__ inline float2 bf2(unsigned u) {
    union { unsigned i; float f; } lo, hi;
    lo.i = u << 16;
    hi.i = u & 0xffff0000u;
    return make_float2(lo.f, hi.f);
}

__device__ inline float2 rfma2(unsigned u, unsigned v, float2 w, float2 acc) {
    float2 uf = bf2(u), vf = bf2(v);
    float2 s = make_float2(uf.x + vf.x, uf.y + vf.y);
    s.x = fmaxf(s.x, 0.f); s.y = fmaxf(s.y, 0.f);
    acc.x = __builtin_fmaf(s.x, w.x, acc.x);
    acc.y = __builtin_fmaf(s.y, w.y, acc.y);
    return acc;
}

__global__ __launch_bounds__(256) void edge_score(
    const int* __restrict__ ei, const unsigned short* __restrict__ UV,
    const float* __restrict__ W2, const float* __restrict__ B2,
    float* __restrict__ out)
{
    const int t = threadIdx.x;
    const int g = t & 7;
    const int slot = t >> 3;                  // 0..31
    const int e0 = blockIdx.x * 64 + slot;
    const int e1 = e0 + 32;

    const float4* W24 = (const float4*)W2;
    const float4 w0 = W24[g * 4 + 0];
    const float4 w1 = W24[g * 4 + 1];
    const float4 w2 = W24[g * 4 + 2];
    const float4 w3 = W24[g * 4 + 3];

    const int s0 = ei[e0];
    const int d0 = ei[N_EDGES + e0];
    const int s1 = ei[e1];
    const int d1 = ei[N_EDGES + e1];

    const uint4* u0p = (const uint4*)(UV + (size_t)s0 * 256) + g * 2;
    const uint4* v0p = (const uint4*)(UV + (size_t)d0 * 256 + 128) + g * 2;
    const uint4* u1p = (const uint4*)(UV + (size_t)s1 * 256) + g * 2;
    const uint4* v1p = (const uint4*)(UV + (size_t)d1 * 256 + 128) + g * 2;
    const uint4 ua0 = u0p[0], ub0 = u0p[1];
    const uint4 va0 = v0p[0], vb0 = v0p[1];
    const uint4 ua1 = u1p[0], ub1 = u1p[1];
    const uint4 va1 = v1p[0], vb1 = v1p[1];

    float2 A = make_float2(0.f, 0.f), B = make_float2(0.f, 0.f);
    A = rfma2(ua0.x, va0.x, make_float2(w0.x, w0.y), A);
    A = rfma2(ua0.y, va0.y, make_float2(w0.z, w0.w), A);
    A = rfma2(ua0.z, va0.z, make_float2(w1.x, w1.y), A);
    A = rfma2(ua0.w, va0.w, make_float2(w1.z, w1.w), A);
    A = rfma2(ub0.x, vb0.x, make_float2(w2.x, w2.y), A);
    A = rfma2(ub0.y, vb0.y, make_float2(w2.z, w2.w), A);
    A = rfma2(ub0.z, vb0.z, make_float2(w3.x, w3.y), A);
    A = rfma2(ub0.w, vb0.w, make_float2(w3.z, w3.w), A);

    B = rfma2(ua1.x, va1.x, make_float2(w0.x, w0.y), B);
    B = rfma2(ua1.y, va1.y, make_float2(w0.z, w0.w), B);
    B = rfma2(ua1.z, va1.z, make_float2(w1.x, w1.y), B);
    B = rfma2(ua1.w, va1.w, make_float2(w1.z, w1.w), B);
    B = rfma2(ub1.x, vb1.x, make_float2(w2.x, w2.y), B);
    B = rfma2(ub1.y, vb1.y, make_float2(w2.z, w2.w), B);
    B = rfma2(ub1.z, vb1.z, make_float2(w3.x, w3.y), B);
    B = rfma2(ub1.w, vb1.w, make_float2(w3.z, w3.w), B);

    float sa = A.x + A.y;
    float sb = B.x + B.y;
    sa += __shfl_xor(sa, 1, 8);
    sa += __shfl_xor(sa, 2, 8);
    sa += __shfl_xor(sa, 4, 8);
    sb += __shfl_xor(sb, 1, 8);
    sb += __shfl_xor(sb, 2, 8);
    sb += __shfl_xor(sb, 4, 8);

    if (g == 0) {
        float bb = B2[0];
        out[e0] = sa + bb;
        out[e1] = sb + bb;
    }
}

extern "C" void kernel_launch(void* const* d_in, const int* in_sizes, int n_in,
                              void* d_out, int out_size, void* d_ws, size_t ws_size,
                              hipStream_t stream) {
    const float* z  = (const float*)d_in[0];
    const int*   ei = (const int*)d_in[1];
    const float* W1 = (const float*)d_in[2];
    const float* b1 = (const float*)d_in[3];
    const float* W2 = (const float*)d_in[4];
    const float* b2 = (const float*)d_in[5];
    float* out = (float*)d_out;

    unsigned short* UV = (unsigned short*)d_ws;                 // 51.2 MB
    unsigned short* Bt = UV + (size_t)N_NODES * 256;            // 64 KB

    transpose_w1<<<64, 256, 0, stream>>>(W1, Bt);
    precompute_uv_mfma<<<PC_GRID, 256, 0, stream>>>(z, Bt, b1, UV);
    edge_score<<<N_EDGES / 64, 256, 0, stream>>>(ei, UV, W2, b2, out);
}